// Round 8
// baseline (24.951 us; speedup 1.0000x reference)
//
#include <hip/hip_runtime.h>

// Problem constants (from reference): B=16, A=9, H=64, W=64, N=40
#define BB 16
#define AA 9
#define HH 64
#define WW 64
#define NN 40

constexpr int PPB   = AA * HH * WW;        // 36864 proposals per batch
constexpr int BLOCK = 256;
constexpr int BLOCKS_PER_B = PPB / BLOCK;  // 144
constexpr int F4_PER_P     = NN / 4;       // 10 float4s per proposal

typedef float vfloat4 __attribute__((ext_vector_type(4)));

__global__ __launch_bounds__(BLOCK) void iou_kernel(
    const float* __restrict__ anc,      // (A,2)
    const float* __restrict__ grid,     // (B,H,W,2)
    const float* __restrict__ offsets,  // (B,A,H,W,4)
    const float* __restrict__ bboxes,   // (B,N,5)
    float* __restrict__ out)            // (B, A*H*W, N)
{
    __shared__ float4 sbox[NN];         // box x1,y1,x2,y2

    const int tid = threadIdx.x;
    const int blk = blockIdx.x;
    const int b        = blk / BLOCKS_PER_B;
    const int blk_in_b = blk % BLOCKS_PER_B;

    // Stage this batch's boxes into LDS (tiny; only dependency behind the barrier)
    if (tid < NN) {
        const float* bb = bboxes + (size_t)(b * NN + tid) * 5;
        sbox[tid] = make_float4(bb[0], bb[1], bb[2], bb[3]);
    }
    __syncthreads();

    const int p_base = blk_in_b * BLOCK;          // block's first proposal in batch
    const int a = p_base >> 12;                   // block-uniform anchor (256 | 4096)
    const float hwid = anc[a * 2 + 0] * 0.5f;
    const float hhgt = anc[a * 2 + 1] * 0.5f;

    vfloat4* outf4 = reinterpret_cast<vfloat4*>(out) +
                     ((size_t)b * PPB + (size_t)p_base) * F4_PER_P;

    // No proposal LDS, no post-decode barrier: each output float4 recomputes its
    // proposal's decode. Runs of 10 lanes share a proposal -> loads are L1-hot.
    #pragma unroll
    for (int i = 0; i < F4_PER_P; ++i) {
        const unsigned f = (unsigned)(tid + i * BLOCK);    // float4 index in block
        const unsigned p = f / 10u;                        // local proposal (0..255)
        const int n0 = (int)(f - p * 10u) * 4;             // first box index

        const int p_in_b = p_base + (int)p;
        const int hw = p_in_b & 4095;
        const int h  = hw >> 6;
        const int w  = hw & 63;

        const float2 g   = *reinterpret_cast<const float2*>(
            grid + (size_t)((b * HH + h) * WW + w) * 2);
        const float4 off = *reinterpret_cast<const float4*>(
            offsets + ((size_t)b * PPB + p_in_b) * 4);

        const float ax1 = g.x - hwid, ax2 = g.x + hwid;
        const float ay1 = g.y - hhgt, ay2 = g.y + hhgt;
        const float cx = (ax1 + ax2) * 0.5f + off.x;
        const float cy = (ay1 + ay2) * 0.5f + off.y;
        const float pw = (ax2 - ax1) * __expf(off.z);
        const float ph = (ay2 - ay1) * __expf(off.w);
        const float px1 = cx - pw * 0.5f, px2 = cx + pw * 0.5f;
        const float py1 = cy - ph * 0.5f, py2 = cy + ph * 0.5f;
        const float ap  = (px2 - px1) * (py2 - py1);

        vfloat4 res;
        #pragma unroll
        for (int k = 0; k < 4; ++k) {
            const float4 bb4 = sbox[n0 + k];               // ds_read_b128
            const float ab  = (bb4.z - bb4.x) * (bb4.w - bb4.y);
            const float xtl = fmaxf(px1, bb4.x);
            const float ytl = fmaxf(py1, bb4.y);
            const float xbr = fminf(px2, bb4.z);
            const float ybr = fminf(py2, bb4.w);
            const float iw = fmaxf(xbr - xtl, 0.0f);
            const float ih = fmaxf(ybr - ytl, 0.0f);
            const float inter = iw * ih;
            const float den = ap + ab - inter;
            res[k] = inter * __builtin_amdgcn_rcpf(den);
        }
        *reinterpret_cast<float4*>(&outf4[f]) = make_float4(res[0], res[1], res[2], res[3]);
    }
}

extern "C" void kernel_launch(void* const* d_in, const int* in_sizes, int n_in,
                              void* d_out, int out_size, void* d_ws, size_t ws_size,
                              hipStream_t stream) {
    const float* anc     = (const float*)d_in[0];
    const float* grid    = (const float*)d_in[1];
    const float* offsets = (const float*)d_in[2];
    const float* bboxes  = (const float*)d_in[3];
    float* out = (float*)d_out;

    const int nblocks = BB * BLOCKS_PER_B;  // 2304
    iou_kernel<<<nblocks, BLOCK, 0, stream>>>(anc, grid, offsets, bboxes, out);
}

// Round 9
// 21.347 us; speedup vs baseline: 1.1688x; 1.1688x over previous
//
#include <hip/hip_runtime.h>

// Problem constants (from reference): B=16, A=9, H=64, W=64, N=40
#define BB 16
#define AA 9
#define HH 64
#define WW 64
#define NN 40

constexpr int PPB   = AA * HH * WW;        // 36864 proposals per batch
constexpr int BLOCK = 256;
constexpr int BLOCKS_PER_B = PPB / BLOCK;  // 144
constexpr int F4_PER_P     = NN / 4;       // 10 float4s per proposal

__global__ __launch_bounds__(BLOCK) void iou_kernel(
    const float* __restrict__ anc,      // (A,2)
    const float* __restrict__ grid,     // (B,H,W,2)
    const float* __restrict__ offsets,  // (B,A,H,W,4)
    const float* __restrict__ bboxes,   // (B,N,5)
    float* __restrict__ out)            // (B, A*H*W, N)
{
    __shared__ float sbx1[NN], sby1[NN], sbx2[NN], sby2[NN], sba[NN];
    __shared__ float sp[BLOCK][5];      // decoded proposals: x1,y1,x2,y2,area

    const int tid = threadIdx.x;
    const int blk = blockIdx.x;
    const int b        = blk / BLOCKS_PER_B;
    const int blk_in_b = blk % BLOCKS_PER_B;

    // Stage this batch's boxes + areas into LDS
    if (tid < NN) {
        const float* bb = bboxes + (size_t)(b * NN + tid) * 5;
        float x1 = bb[0], y1 = bb[1], x2 = bb[2], y2 = bb[3];
        sbx1[tid] = x1; sby1[tid] = y1;
        sbx2[tid] = x2; sby2[tid] = y2;
        sba[tid]  = (x2 - x1) * (y2 - y1);
    }

    // --- Phase 1: each thread decodes one proposal into LDS ---
    const int p_in_b = blk_in_b * BLOCK + tid;   // proposal index within batch
    const int a  = p_in_b >> 12;                 // / (H*W) = /4096
    const int hw = p_in_b & 4095;
    const int h  = hw >> 6;
    const int w  = hw & 63;

    const float hwid = anc[a * 2 + 0] * 0.5f;
    const float hhgt = anc[a * 2 + 1] * 0.5f;

    const float2 g   = *reinterpret_cast<const float2*>(grid + (size_t)((b * HH + h) * WW + w) * 2);
    const float4 off = *reinterpret_cast<const float4*>(offsets + (size_t)(b * PPB + p_in_b) * 4);

    const float ax1 = g.x - hwid, ax2 = g.x + hwid;
    const float ay1 = g.y - hhgt, ay2 = g.y + hhgt;
    const float cx = (ax1 + ax2) * 0.5f + off.x;
    const float cy = (ay1 + ay2) * 0.5f + off.y;
    const float pw = (ax2 - ax1) * __expf(off.z);
    const float ph = (ay2 - ay1) * __expf(off.w);
    const float px1 = cx - pw * 0.5f, px2 = cx + pw * 0.5f;
    const float py1 = cy - ph * 0.5f, py2 = cy + ph * 0.5f;

    sp[tid][0] = px1;
    sp[tid][1] = py1;
    sp[tid][2] = px2;
    sp[tid][3] = py2;
    sp[tid][4] = (px2 - px1) * (py2 - py1);

    __syncthreads();

    // --- Phase 2: coalesced output sweep over the block's 2560 float4s ---
    float4* outf4 = reinterpret_cast<float4*>(out) +
                    (size_t)(b * PPB + blk_in_b * BLOCK) * F4_PER_P;

    #pragma unroll
    for (int i = 0; i < F4_PER_P; ++i) {
        const unsigned f = (unsigned)(tid + i * BLOCK);    // float4 index in block
        const unsigned p = f / 10u;                        // proposal (compiler -> mulhi)
        const int n0 = (int)(f - p * 10u) * 4;             // first box index

        const float qx1 = sp[p][0];
        const float qy1 = sp[p][1];
        const float qx2 = sp[p][2];
        const float qy2 = sp[p][3];
        const float ap  = sp[p][4];

        float res[4];
        #pragma unroll
        for (int k = 0; k < 4; ++k) {
            const int n = n0 + k;
            const float xtl = fmaxf(qx1, sbx1[n]);
            const float ytl = fmaxf(qy1, sby1[n]);
            const float xbr = fminf(qx2, sbx2[n]);
            const float ybr = fminf(qy2, sby2[n]);
            const float iw = fmaxf(xbr - xtl, 0.0f);
            const float ih = fmaxf(ybr - ytl, 0.0f);
            const float inter = iw * ih;
            const float den = ap + sba[n] - inter;
            res[k] = inter * __builtin_amdgcn_rcpf(den);
        }
        outf4[f] = make_float4(res[0], res[1], res[2], res[3]);
    }
}

extern "C" void kernel_launch(void* const* d_in, const int* in_sizes, int n_in,
                              void* d_out, int out_size, void* d_ws, size_t ws_size,
                              hipStream_t stream) {
    const float* anc     = (const float*)d_in[0];
    const float* grid    = (const float*)d_in[1];
    const float* offsets = (const float*)d_in[2];
    const float* bboxes  = (const float*)d_in[3];
    float* out = (float*)d_out;

    const int nblocks = BB * BLOCKS_PER_B;  // 2304
    iou_kernel<<<nblocks, BLOCK, 0, stream>>>(anc, grid, offsets, bboxes, out);
}